// Round 1
// baseline (671.304 us; speedup 1.0000x reference)
//
#include <hip/hip_runtime.h>

// RandLANet attentive pooling forward, fp32 baseline.
// Pipeline: K0 transpose [B,C,N]->[BN,C] ; K1 fused gather+attn+linear
// (writes pre-BN out in [B,OUT,N] + per-block BN partials) ; K2 reduce
// partials -> per-channel scale/shift ; K3 apply BN in place.

#define NPTS   16384
#define BATCH  4
#define BNPTS  (BATCH*NPTS)   // 65536
#define CIN    64
#define KNB    16
#define COUT   128
#define K1_BLOCKS 1024
#define BN_EPS 1e-5f

// ---------------- K0: feature [B][C][N] -> flat [B*N][C] ----------------
__global__ __launch_bounds__(256) void k_transpose_in(
    const float* __restrict__ feat, float* __restrict__ flat)
{
    __shared__ float t[CIN][CIN + 1];
    int blk  = blockIdx.x;            // 0..1023
    int b    = blk >> 8;              // /256
    int n0   = (blk & 255) << 6;      // *64
    int tid  = threadIdx.x;
    int sub  = tid >> 6;              // 0..3
    int lane = tid & 63;

    const float* fb = feat + (long)b * CIN * NPTS;
    #pragma unroll
    for (int r = 0; r < CIN; r += 4) {
        int c = r + sub;
        t[c][lane] = fb[(long)c * NPTS + n0 + lane];   // coalesced along n
    }
    __syncthreads();
    float* ob = flat + (long)(b * NPTS + n0) * CIN;
    #pragma unroll
    for (int r = 0; r < CIN; r += 4) {
        int x = r + sub;
        ob[(long)x * CIN + lane] = t[lane][x];         // coalesced along c
    }
}

// ---------------- K1: fused gather + attention pool + linear ----------------
// One wave per point; lane = channel d (and c). 1024 blocks x 4 waves,
// 16 points per wave.
__global__ __launch_bounds__(256) void k_attn(
    const float* __restrict__ flat, const int* __restrict__ nidx,
    const float* __restrict__ Wm,   const float* __restrict__ Wc,
    const float* __restrict__ bc,   float* __restrict__ out,
    float* __restrict__ part)
{
    __shared__ float wc_lds[COUT][CIN + 1];   // 33.28 KB, stride 65 -> conflict-free
    __shared__ float s_lds[4][KNB][CIN];      // 16 KB (reused for final reduce)
    __shared__ float pool_lds[4][CIN];        // 1 KB

    int tid  = threadIdx.x;
    int lane = tid & 63;
    int wv   = tid >> 6;

    for (int e = tid; e < COUT * CIN; e += 256)
        wc_lds[e >> 6][e & 63] = Wc[e];

    float wm[CIN];   // lane d holds W_mlp row d
    {
        const float4* w4 = (const float4*)(Wm + lane * CIN);
        #pragma unroll
        for (int q = 0; q < CIN / 4; ++q) {
            float4 v = w4[q];
            wm[4*q+0] = v.x; wm[4*q+1] = v.y; wm[4*q+2] = v.z; wm[4*q+3] = v.w;
        }
    }
    float b0 = bc[lane], b1 = bc[lane + 64];
    __syncthreads();

    float s0 = 0.f, s1 = 0.f, q0 = 0.f, q1 = 0.f;   // BN partial sums

    int gw = (blockIdx.x << 2) + wv;
    for (int i = gw; i < BNPTS; i += K1_BLOCKS * 4) {
        const int4* ip = (const int4*)(nidx + (long)i * KNB);
        int4 ia = ip[0], ib = ip[1], ic = ip[2], id = ip[3];
        int idxs[KNB] = { ia.x, ia.y, ia.z, ia.w,  ib.x, ib.y, ib.z, ib.w,
                          ic.x, ic.y, ic.z, ic.w,  id.x, id.y, id.z, id.w };

        float sreg[KNB];
        #pragma unroll
        for (int k = 0; k < KNB; ++k) {
            float v = flat[(long)idxs[k] * CIN + lane];   // 256B coalesced gather
            sreg[k] = v;
            s_lds[wv][k][lane] = v;
        }

        float pooled = 0.f;
        #pragma unroll
        for (int k = 0; k < KNB; ++k) {
            float sc = 0.f;
            #pragma unroll
            for (int c = 0; c < CIN; ++c)
                sc = fmaf(wm[c], s_lds[wv][k][c], sc);    // LDS broadcast reads
            // softmax over channel dim == over lanes
            float m = sc;
            #pragma unroll
            for (int off = 32; off >= 1; off >>= 1)
                m = fmaxf(m, __shfl_xor(m, off));
            float e = __expf(sc - m);
            float sum = e;
            #pragma unroll
            for (int off = 32; off >= 1; off >>= 1)
                sum += __shfl_xor(sum, off);
            pooled = fmaf(e / sum, sreg[k], pooled);
        }

        pool_lds[wv][lane] = pooled;
        float o0 = b0, o1 = b1;
        #pragma unroll
        for (int c = 0; c < CIN; ++c) {
            float p = pool_lds[wv][c];                    // broadcast
            o0 = fmaf(wc_lds[lane][c],      p, o0);       // stride-65: 2-way, free
            o1 = fmaf(wc_lds[lane + 64][c], p, o1);
        }

        s0 += o0; q0 = fmaf(o0, o0, q0);
        s1 += o1; q1 = fmaf(o1, o1, q1);

        int b = i >> 14;            // / NPTS
        int n = i & (NPTS - 1);
        out[((long)((b << 7) + lane)      << 14) + n] = o0;
        out[((long)((b << 7) + lane + 64) << 14) + n] = o1;
    }

    // block-level BN partial reduction; reuse s_lds as [4][1024] scratch
    float* red = &s_lds[0][0][0];
    red[wv * 1024 + lane]       = s0;   // sum   ch = lane
    red[wv * 1024 + 64  + lane] = s1;   // sum   ch = lane+64
    red[wv * 1024 + 128 + lane] = q0;   // sumsq ch = lane
    red[wv * 1024 + 192 + lane] = q1;   // sumsq ch = lane+64
    __syncthreads();
    float v = red[tid] + red[1024 + tid] + red[2048 + tid] + red[3072 + tid];
    part[(long)blockIdx.x * 256 + tid] = v;   // [0:128)=sum, [128:256)=sumsq
}

// ---------------- K2: reduce partials -> scale/shift ----------------
__global__ __launch_bounds__(1024) void k_stats(
    const float* __restrict__ part, const float* __restrict__ gamma,
    const float* __restrict__ beta, float* __restrict__ scalesh)
{
    __shared__ float buf[4][256];
    __shared__ float tot[256];
    int t   = threadIdx.x;
    int col = t & 255;
    int seg = t >> 8;     // 0..3
    float v = 0.f;
    #pragma unroll 8
    for (int r = seg * 256; r < seg * 256 + 256; ++r)
        v += part[(long)r * 256 + col];
    buf[seg][col] = v;
    __syncthreads();
    if (t < 256)
        tot[t] = buf[0][t] + buf[1][t] + buf[2][t] + buf[3][t];
    __syncthreads();
    if (t < 128) {
        float mean = tot[t]       * (1.0f / BNPTS);
        float ex2  = tot[128 + t] * (1.0f / BNPTS);
        float var  = ex2 - mean * mean;
        float sc   = gamma[t] * rsqrtf(var + BN_EPS);
        scalesh[t]       = sc;
        scalesh[128 + t] = beta[t] - mean * sc;
    }
}

// ---------------- K3: apply BN in place on out [B][OUT][N] ----------------
__global__ __launch_bounds__(256) void k_apply(
    float* __restrict__ out, const float* __restrict__ scalesh)
{
    __shared__ float sc[COUT], sh[COUT];
    int tid = threadIdx.x;
    if (tid < COUT) { sc[tid] = scalesh[tid]; sh[tid] = scalesh[128 + tid]; }
    __syncthreads();
    const int total4 = BATCH * COUT * NPTS / 4;   // 2,097,152 float4s
    for (long i = (long)blockIdx.x * 256 + tid; i < total4;
         i += (long)gridDim.x * 256) {
        int ch = ((int)(i >> 12)) & 127;          // (i*4 / N) % OUT
        float4 v = ((float4*)out)[i];
        float a = sc[ch], b = sh[ch];
        v.x = fmaf(v.x, a, b); v.y = fmaf(v.y, a, b);
        v.z = fmaf(v.z, a, b); v.w = fmaf(v.w, a, b);
        ((float4*)out)[i] = v;
    }
}

extern "C" void kernel_launch(void* const* d_in, const int* in_sizes, int n_in,
                              void* d_out, int out_size, void* d_ws, size_t ws_size,
                              hipStream_t stream)
{
    const float* feat  = (const float*)d_in[0];
    const int*   nidx  = (const int*)  d_in[1];
    // d_in[2] = permatrix (unused by forward)
    const float* Wm    = (const float*)d_in[3];
    const float* Wc    = (const float*)d_in[4];
    const float* bc    = (const float*)d_in[5];
    const float* gamma = (const float*)d_in[6];
    const float* beta  = (const float*)d_in[7];
    float* out = (float*)d_out;

    float* flat    = (float*)d_ws;                       // BNPTS*CIN      (16.8 MB)
    float* part    = flat + (size_t)BNPTS * CIN;         // K1_BLOCKS*256  ( 1.0 MB)
    float* scalesh = part + (size_t)K1_BLOCKS * 256;     // 256

    k_transpose_in<<<1024, 256, 0, stream>>>(feat, flat);
    k_attn<<<K1_BLOCKS, 256, 0, stream>>>(flat, nidx, Wm, Wc, bc, out, part);
    k_stats<<<1, 1024, 0, stream>>>(part, gamma, beta, scalesh);
    k_apply<<<2048, 256, 0, stream>>>(out, scalesh);
}

// Round 2
// 152.575 us; speedup vs baseline: 4.3998x; 4.3998x over previous
//
#include <hip/hip_runtime.h>
#include <cstdint>

#define NPTS   16384
#define BATCH  4
#define BNP    65536
#define CIN    64
#define KNB    16
#define COUT   128
#define BN_EPS 1e-5f

typedef __attribute__((ext_vector_type(8))) short     short8;
typedef __attribute__((ext_vector_type(4))) float     f32x4;
typedef __attribute__((ext_vector_type(2))) unsigned  u32x2;
typedef __attribute__((ext_vector_type(4))) int       i32x4;

// wait until <= n vector-memory ops outstanding (lgkm=15, exp=7 = no wait)
#define WAITVM(n) __builtin_amdgcn_s_waitcnt(0x0F70 | (n))

__device__ __forceinline__ unsigned short f2bf(float f) {   // RNE
    unsigned u = __float_as_uint(f);
    u += 0x7FFFu + ((u >> 16) & 1u);
    return (unsigned short)(u >> 16);
}
__device__ __forceinline__ float bf2f(unsigned short h) {
    return __uint_as_float(((unsigned)h) << 16);
}

// ---------------- K0: feature [B][C][N] -> flat bf16 [B*N][64] ----------------
__global__ __launch_bounds__(256) void k_prep(const float* __restrict__ feat,
                                              unsigned short* __restrict__ fb)
{
    __shared__ float t[CIN][CIN + 1];
    int blk = blockIdx.x;
    int b   = blk >> 8;
    int n0  = (blk & 255) << 6;
    int sub = threadIdx.x >> 6, lane = threadIdx.x & 63;
    const float* fp = feat + (size_t)b * CIN * NPTS;
    #pragma unroll
    for (int r = 0; r < CIN; r += 4) {
        int c = r + sub;
        t[c][lane] = fp[(size_t)c * NPTS + n0 + lane];     // coalesced along n
    }
    __syncthreads();
    unsigned short* ob = fb + (size_t)(b * NPTS + n0) * CIN;
    #pragma unroll
    for (int r = 0; r < CIN; r += 4) {
        int x = r + sub;
        ob[(size_t)x * CIN + lane] = f2bf(t[lane][x]);     // row n0+x, ch=lane
    }
}

// ---------------- K1: MFMA gather+attention+linear ----------------
// Per wave: 16 points x 16 neighbors. Phase1: score^T[d,pt]=Wm x spir^T (MFMA).
// Softmax over d: 16 in-lane exps + 2 shuffles. P=attn*spir -> LDS -> B-frags.
// Phase2: D[o,pt] += Wc x P_k accumulated over k (pool+linear fused into MFMA).
// LDS slices are wave-private: NO __syncthreads in main loop.
__global__ __launch_bounds__(256, 2) void k_main(
    const unsigned short* __restrict__ fb,   // [BNP][64] bf16
    const int* __restrict__ nidx,            // [BNP][16]
    const float* __restrict__ Wm,            // [64][64]
    const float* __restrict__ Wc,            // [128][64]
    float* __restrict__ out)                 // [4][128][16384], pre-BN
{
    // layout within a spir buffer (bytes): pt*64 + (ch&31)*2 + (ch>>5)*1024
    // == exactly global_load_lds's "base + lane*16" for lane=(pt<<2)|q
    __shared__ __align__(16) unsigned short spir[4][2][1024]; // 2KB/buf, dbuf
    __shared__ __align__(16) unsigned short plds[4][16 * 72]; // pad 72: bank-safe
    __shared__ __align__(16) int            idxl[4][16 * 20]; // stride 20: 2-way max

    const int tid  = threadIdx.x;
    const int wv   = tid >> 6;
    const int lane = tid & 63;
    const int ptc  = lane & 15;     // MFMA n / m index
    const int qg   = lane >> 4;     // quad group
    const int pt4  = lane >> 2;     // gather row
    const int q4   = lane & 3;      // gather quarter

    // ---- weight A-fragments in registers: A[m=lane&15][k=qg*8+j (+32*ks)] ----
    short8 wmF[4][2];
    #pragma unroll
    for (int mt = 0; mt < 4; ++mt)
        #pragma unroll
        for (int ks = 0; ks < 2; ++ks) {
            const float* p = Wm + (size_t)(mt * 16 + ptc) * CIN + qg * 8 + ks * 32;
            short8 v;
            #pragma unroll
            for (int j = 0; j < 8; ++j) v[j] = (short)f2bf(p[j]);
            wmF[mt][ks] = v;
        }
    short8 wcF[8][2];
    #pragma unroll
    for (int mt = 0; mt < 8; ++mt)
        #pragma unroll
        for (int ks = 0; ks < 2; ++ks) {
            const float* p = Wc + (size_t)(mt * 16 + ptc) * CIN + qg * 8 + ks * 32;
            short8 v;
            #pragma unroll
            for (int j = 0; j < 8; ++j) v[j] = (short)f2bf(p[j]);
            wcF[mt][ks] = v;
        }

    f32x4 acc2[8];
    #pragma unroll
    for (int i = 0; i < 8; ++i) acc2[i] = (f32x4){0.f, 0.f, 0.f, 0.f};

    for (int g = blockIdx.x * 4 + wv; g < BNP / KNB; g += 2048) {
        // stage this group's 256 neighbor indices
        i32x4 iv = *(const i32x4*)(nidx + (size_t)g * 256 + lane * 4);
        *(i32x4*)&idxl[wv][pt4 * 20 + q4 * 4] = iv;

        // async gather of neighbor k's 16 rows (2KB) into buf bf
        auto issue_gather = [&](int k, int bf) {
            int id = idxl[wv][pt4 * 20 + k];               // 4-lane broadcast read
            const unsigned short* gp = fb + (size_t)id * CIN + q4 * 8;
            __builtin_amdgcn_global_load_lds(
                (const __attribute__((address_space(1))) unsigned int*)(const void*)gp,
                (__attribute__((address_space(3))) unsigned int*)(void*)&spir[wv][bf][0],
                16, 0, 0);
            __builtin_amdgcn_global_load_lds(
                (const __attribute__((address_space(1))) unsigned int*)(const void*)(gp + 32),
                (__attribute__((address_space(3))) unsigned int*)(void*)&spir[wv][bf][512],
                16, 0, 0);
        };

        issue_gather(0, 0);
        issue_gather(1, 1);

        #pragma unroll
        for (int k = 0; k < KNB; ++k) {
            const int bf = k & 1;
            if (k < KNB - 1) WAITVM(2); else WAITVM(0);    // buf k landed
            __asm__ volatile("" ::: "memory");

            // ---- phase 1: score^T[d, pt] = Wm x spir^T ----
            short8 b1_0 = *(const short8*)&spir[wv][bf][      ptc * 32 + qg * 8];
            short8 b1_1 = *(const short8*)&spir[wv][bf][512 + ptc * 32 + qg * 8];
            f32x4 zero4 = (f32x4){0.f, 0.f, 0.f, 0.f};
            f32x4 a1[4];
            #pragma unroll
            for (int mt = 0; mt < 4; ++mt) {
                f32x4 t0 = __builtin_amdgcn_mfma_f32_16x16x32_bf16(wmF[mt][0], b1_0, zero4, 0, 0, 0);
                a1[mt]   = __builtin_amdgcn_mfma_f32_16x16x32_bf16(wmF[mt][1], b1_1, t0,    0, 0, 0);
            }

            // ---- softmax over d (in-lane 16 + xor16/xor32) ----
            float e[16], s = 0.f;
            #pragma unroll
            for (int mt = 0; mt < 4; ++mt)
                #pragma unroll
                for (int r = 0; r < 4; ++r) {
                    float x = __expf(a1[mt][r]);
                    e[mt * 4 + r] = x;
                    s += x;
                }
            s += __shfl_xor(s, 16);
            s += __shfl_xor(s, 32);
            float inv = __builtin_amdgcn_rcpf(s);

            // ---- P = attn (.) spir  -> plds (bf16, B-layout staging) ----
            #pragma unroll
            for (int mt = 0; mt < 4; ++mt) {
                // spir channels d0..d0+3, d0 = 16*mt + 4*qg (row ptc)
                u32x2 sv = *(const u32x2*)&spir[wv][bf]
                    [(mt >> 1) * 512 + ptc * 32 + (mt & 1) * 16 + qg * 4];
                unsigned lo = sv[0], hi = sv[1];
                float p0 = bf2f((unsigned short)lo)         * (e[mt * 4 + 0] * inv);
                float p1 = bf2f((unsigned short)(lo >> 16)) * (e[mt * 4 + 1] * inv);
                float p2 = bf2f((unsigned short)hi)         * (e[mt * 4 + 2] * inv);
                float p3 = bf2f((unsigned short)(hi >> 16)) * (e[mt * 4 + 3] * inv);
                unsigned w0 = ((__float_as_uint(p0) + 0x8000u) >> 16) |
                              ((__float_as_uint(p1) + 0x8000u) & 0xFFFF0000u);
                unsigned w1 = ((__float_as_uint(p2) + 0x8000u) >> 16) |
                              ((__float_as_uint(p3) + 0x8000u) & 0xFFFF0000u);
                *(u32x2*)&plds[wv][ptc * 72 + mt * 16 + qg * 4] = (u32x2){w0, w1};
            }

            // ---- B2 frags: P[pt=lane&15][d=qg*8+j+32ks] ----
            short8 b2_0 = *(const short8*)&plds[wv][ptc * 72 +      qg * 8];
            short8 b2_1 = *(const short8*)&plds[wv][ptc * 72 + 32 + qg * 8];

            if (k < KNB - 2) issue_gather(k + 2, bf);      // dbuf refill

            // ---- phase 2: D[o, pt] += Wc x P_k (pool+linear fused) ----
            #pragma unroll
            for (int mt = 0; mt < 8; ++mt) {
                acc2[mt] = __builtin_amdgcn_mfma_f32_16x16x32_bf16(wcF[mt][0], b2_0, acc2[mt], 0, 0, 0);
                acc2[mt] = __builtin_amdgcn_mfma_f32_16x16x32_bf16(wcF[mt][1], b2_1, acc2[mt], 0, 0, 0);
            }
        }

        // ---- epilogue: C-layout store, out[b][o][n]  (b_conv absorbed by BN) ----
        int p0 = g * KNB;
        int b  = p0 >> 14;
        int nn = (p0 & (NPTS - 1)) + ptc;
        float* ob = out + (((size_t)b * COUT) << 14) + nn;
        #pragma unroll
        for (int mt = 0; mt < 8; ++mt)
            #pragma unroll
            for (int r = 0; r < 4; ++r) {
                ob[((size_t)(mt * 16 + qg * 4 + r)) << 14] = acc2[mt][r];
                acc2[mt][r] = 0.f;
            }
    }
}

// ---------------- K2: deterministic BN partials, one block per (o, b) ----------------
__global__ __launch_bounds__(256) void k_part(const float* __restrict__ out,
                                              float* __restrict__ part)
{
    int o = blockIdx.x >> 2, b = blockIdx.x & 3;
    const float4* p = (const float4*)(out + (((size_t)(b * COUT + o)) << 14));
    float s = 0.f, q = 0.f;
    for (int i = threadIdx.x; i < NPTS / 4; i += 256) {
        float4 v = p[i];
        s += (v.x + v.y) + (v.z + v.w);
        q += (v.x * v.x + v.y * v.y) + (v.z * v.z + v.w * v.w);
    }
    #pragma unroll
    for (int off = 32; off >= 1; off >>= 1) {
        s += __shfl_xor(s, off);
        q += __shfl_xor(q, off);
    }
    __shared__ float ls[4], lq[4];
    if ((threadIdx.x & 63) == 0) { ls[threadIdx.x >> 6] = s; lq[threadIdx.x >> 6] = q; }
    __syncthreads();
    if (threadIdx.x == 0) {
        part[blockIdx.x * 2]     = (ls[0] + ls[1]) + (ls[2] + ls[3]);
        part[blockIdx.x * 2 + 1] = (lq[0] + lq[1]) + (lq[2] + lq[3]);
    }
}

// ---------------- K3: finalize stats per block + apply BN in place ----------------
__global__ __launch_bounds__(256) void k_apply(float* __restrict__ out,
                                               const float* __restrict__ part,
                                               const float* __restrict__ gamma,
                                               const float* __restrict__ beta)
{
    __shared__ float sc[COUT], sh[COUT];
    int t = threadIdx.x;
    if (t < COUT) {
        float s = 0.f, q = 0.f;
        #pragma unroll
        for (int j = 0; j < 4; ++j) {
            s += part[(t * 4 + j) * 2];
            q += part[(t * 4 + j) * 2 + 1];
        }
        float mean = s * (1.0f / BNP);
        float var  = q * (1.0f / BNP) - mean * mean;
        float a = gamma[t] * rsqrtf(var + BN_EPS);
        sc[t] = a; sh[t] = beta[t] - mean * a;
    }
    __syncthreads();
    const int total4 = BATCH * COUT * NPTS / 4;
    for (long i = (long)blockIdx.x * 256 + t; i < total4; i += (long)gridDim.x * 256) {
        int ch = ((int)(i >> 12)) & 127;
        float4 v = ((float4*)out)[i];
        float a = sc[ch], b2 = sh[ch];
        v.x = fmaf(v.x, a, b2); v.y = fmaf(v.y, a, b2);
        v.z = fmaf(v.z, a, b2); v.w = fmaf(v.w, a, b2);
        ((float4*)out)[i] = v;
    }
}

extern "C" void kernel_launch(void* const* d_in, const int* in_sizes, int n_in,
                              void* d_out, int out_size, void* d_ws, size_t ws_size,
                              hipStream_t stream)
{
    const float* feat  = (const float*)d_in[0];
    const int*   nidx  = (const int*)  d_in[1];
    // d_in[2] = permatrix (unused); d_in[5] = b_conv (exactly absorbed by BN)
    const float* Wm    = (const float*)d_in[3];
    const float* Wc    = (const float*)d_in[4];
    const float* gamma = (const float*)d_in[6];
    const float* beta  = (const float*)d_in[7];
    float* out = (float*)d_out;

    unsigned short* fb = (unsigned short*)d_ws;                        // 8.4 MB
    float* part = (float*)((char*)d_ws + (size_t)BNP * CIN * 2);       // 1024 floats

    k_prep <<<1024, 256, 0, stream>>>(feat, fb);
    k_main <<<512,  256, 0, stream>>>(fb, nidx, Wm, Wc, out);
    k_part <<<512,  256, 0, stream>>>(out, part);
    k_apply<<<2048, 256, 0, stream>>>(out, part, gamma, beta);
}